// Round 1
// baseline (3393.896 us; speedup 1.0000x reference)
//
#include <hip/hip_runtime.h>
#include <math.h>
#include <cstddef>
#include <cstdint>

#define B_ 8
#define S_ 4096
#define D_ 256

// ---------------------------------------------------------------------------
// GEMM: C[M,256] = A[M,256] @ W[256,256] + bias   (M = 32768, fp32)
// Tile 64x64, K-tile 16, 256 threads, 4x4 micro-tile per thread.
// As stored transposed [k][m] so inner loop reads are 16-lane broadcasts.
// ---------------------------------------------------------------------------
__global__ __launch_bounds__(256) void gemm_bias_kernel(
    const float* __restrict__ A, const float* __restrict__ W,
    const float* __restrict__ bias, float* __restrict__ C) {
  __shared__ __align__(16) float As[16][68];
  __shared__ __align__(16) float Ws[16][68];
  const int t  = threadIdx.x;
  const int tx = t & 15, ty = t >> 4;
  const size_t m0 = (size_t)blockIdx.x * 64;
  const int    n0 = blockIdx.y * 64;

  float acc[4][4] = {};

  const int ar  = t >> 2;         // 0..63  A-tile row
  const int ac4 = (t & 3) << 2;   // 0,4,8,12  A-tile col (float4)
  const int wk  = t >> 4;         // 0..15  W-tile row
  const int wn  = (t & 15) << 2;  // 0..60  W-tile col (float4)

  for (int k0 = 0; k0 < 256; k0 += 16) {
    const float4 a4 = *(const float4*)(A + (m0 + ar) * 256 + k0 + ac4);
    const float4 w4 = *(const float4*)(W + (size_t)(k0 + wk) * 256 + n0 + wn);
    As[ac4 + 0][ar] = a4.x; As[ac4 + 1][ar] = a4.y;
    As[ac4 + 2][ar] = a4.z; As[ac4 + 3][ar] = a4.w;
    *(float4*)&Ws[wk][wn] = w4;
    __syncthreads();
#pragma unroll
    for (int kk = 0; kk < 16; ++kk) {
      const float4 av = *(const float4*)&As[kk][ty << 2];
      const float4 bv = *(const float4*)&Ws[kk][tx << 2];
      acc[0][0] += av.x * bv.x; acc[0][1] += av.x * bv.y;
      acc[0][2] += av.x * bv.z; acc[0][3] += av.x * bv.w;
      acc[1][0] += av.y * bv.x; acc[1][1] += av.y * bv.y;
      acc[1][2] += av.y * bv.z; acc[1][3] += av.y * bv.w;
      acc[2][0] += av.z * bv.x; acc[2][1] += av.z * bv.y;
      acc[2][2] += av.z * bv.z; acc[2][3] += av.z * bv.w;
      acc[3][0] += av.w * bv.x; acc[3][1] += av.w * bv.y;
      acc[3][2] += av.w * bv.z; acc[3][3] += av.w * bv.w;
    }
    __syncthreads();
  }

  const float4 bv4 = *(const float4*)(bias + n0 + (tx << 2));
#pragma unroll
  for (int i = 0; i < 4; ++i) {
    float4 o;
    o.x = acc[i][0] + bv4.x; o.y = acc[i][1] + bv4.y;
    o.z = acc[i][2] + bv4.z; o.w = acc[i][3] + bv4.w;
    *(float4*)(C + (m0 + (ty << 2) + i) * 256 + n0 + (tx << 2)) = o;
  }
}

// ---------------------------------------------------------------------------
// Flash attention, fp32.  Grid (S/64, B), 256 threads.
// Per block: 64 q-rows. K/V streamed in 64-row tiles, D chunked by 64.
// Q,K chunks staged TRANSPOSED [dk][row] -> inner-loop LDS reads are
// broadcast (conflict-free).  V staged natural [j][d].
// LDS ~52 KB -> 3 blocks/CU.
// ---------------------------------------------------------------------------
__global__ __launch_bounds__(256, 3) void flash_attn_kernel(
    const float* __restrict__ q, const float* __restrict__ k,
    const float* __restrict__ v, float* __restrict__ ctx) {
  __shared__ __align__(16) float bufA[64][68];  // q^T chunk, later v chunk
  __shared__ __align__(16) float bufB[64][68];  // k^T chunk
  __shared__ float pT[64][65];                  // probs [qrow][j]
  __shared__ float mrow[64], lrow[64], arow[64];

  const int t  = threadIdx.x;
  const int tx = t & 15, ty = t >> 4;
  const int q0 = blockIdx.x * 64;
  const int b  = blockIdx.y;
  const size_t base = (size_t)b * S_ * D_;

  float acc[4][16] = {};  // [row i][dc*4 + c]

  if (t < 64) { mrow[t] = -INFINITY; lrow[t] = 0.f; }
  __syncthreads();

  for (int jt = 0; jt < 64; ++jt) {
    const int j0 = jt * 64;
    float s[4][4] = {};

    // ---- scores: S = Q @ K^T over D in 4 chunks of 64 ----
    for (int dc = 0; dc < 4; ++dc) {
      const int d0 = dc << 6;
#pragma unroll
      for (int l = 0; l < 4; ++l) {
        const int idx = t + (l << 8);
        const int r   = idx >> 4;
        const int c4  = (idx & 15) << 2;
        const float4 qv = *(const float4*)(q + base + (size_t)(q0 + r) * D_ + d0 + c4);
        bufA[c4 + 0][r] = qv.x; bufA[c4 + 1][r] = qv.y;
        bufA[c4 + 2][r] = qv.z; bufA[c4 + 3][r] = qv.w;
        const float4 kv = *(const float4*)(k + base + (size_t)(j0 + r) * D_ + d0 + c4);
        bufB[c4 + 0][r] = kv.x; bufB[c4 + 1][r] = kv.y;
        bufB[c4 + 2][r] = kv.z; bufB[c4 + 3][r] = kv.w;
      }
      __syncthreads();
#pragma unroll
      for (int dk = 0; dk < 64; ++dk) {
        const float4 qa = *(const float4*)&bufA[dk][ty << 2];
        const float4 kb = *(const float4*)&bufB[dk][tx << 2];
        s[0][0] += qa.x * kb.x; s[0][1] += qa.x * kb.y;
        s[0][2] += qa.x * kb.z; s[0][3] += qa.x * kb.w;
        s[1][0] += qa.y * kb.x; s[1][1] += qa.y * kb.y;
        s[1][2] += qa.y * kb.z; s[1][3] += qa.y * kb.w;
        s[2][0] += qa.z * kb.x; s[2][1] += qa.z * kb.y;
        s[2][2] += qa.z * kb.z; s[2][3] += qa.z * kb.w;
        s[3][0] += qa.w * kb.x; s[3][1] += qa.w * kb.y;
        s[3][2] += qa.w * kb.z; s[3][3] += qa.w * kb.w;
      }
      __syncthreads();
    }

    // ---- write scaled scores to pT (scalar writes; stride 65 keeps the
    //      row-owner scan conflict-free) ----
#pragma unroll
    for (int i = 0; i < 4; ++i) {
#pragma unroll
      for (int c = 0; c < 4; ++c)
        pT[(ty << 2) + i][(tx << 2) + c] = s[i][c] * 0.0625f;  // 1/sqrt(256)
    }
    __syncthreads();

    // ---- online softmax update, one thread per q-row ----
    if (t < 64) {
      const float mold = mrow[t];
      float mx = mold;
#pragma unroll 16
      for (int j = 0; j < 64; ++j) mx = fmaxf(mx, pT[t][j]);
      const float alpha = __expf(mold - mx);
      float sum = 0.f;
#pragma unroll 16
      for (int j = 0; j < 64; ++j) {
        const float e = __expf(pT[t][j] - mx);
        pT[t][j] = e;
        sum += e;
      }
      mrow[t] = mx;
      lrow[t] = lrow[t] * alpha + sum;
      arow[t] = alpha;
    }
    __syncthreads();

    // ---- rescale accumulators ----
#pragma unroll
    for (int i = 0; i < 4; ++i) {
      const float al = arow[(ty << 2) + i];
#pragma unroll
      for (int c = 0; c < 16; ++c) acc[i][c] *= al;
    }

    // ---- PV: ctx += P @ V, D in 4 chunks of 64 ----
#pragma unroll
    for (int dc = 0; dc < 4; ++dc) {
      const int d0 = dc << 6;
#pragma unroll
      for (int l = 0; l < 4; ++l) {
        const int idx = t + (l << 8);
        const int r   = idx >> 4;
        const int c4  = (idx & 15) << 2;
        *(float4*)&bufA[r][c4] =
            *(const float4*)(v + base + (size_t)(j0 + r) * D_ + d0 + c4);
      }
      __syncthreads();
      const int co = dc << 2;
#pragma unroll
      for (int j = 0; j < 64; ++j) {
        const float4 v4 = *(const float4*)&bufA[j][tx << 2];
        const float p0 = pT[(ty << 2) + 0][j];
        const float p1 = pT[(ty << 2) + 1][j];
        const float p2 = pT[(ty << 2) + 2][j];
        const float p3 = pT[(ty << 2) + 3][j];
        acc[0][co + 0] += p0 * v4.x; acc[0][co + 1] += p0 * v4.y;
        acc[0][co + 2] += p0 * v4.z; acc[0][co + 3] += p0 * v4.w;
        acc[1][co + 0] += p1 * v4.x; acc[1][co + 1] += p1 * v4.y;
        acc[1][co + 2] += p1 * v4.z; acc[1][co + 3] += p1 * v4.w;
        acc[2][co + 0] += p2 * v4.x; acc[2][co + 1] += p2 * v4.y;
        acc[2][co + 2] += p2 * v4.z; acc[2][co + 3] += p2 * v4.w;
        acc[3][co + 0] += p3 * v4.x; acc[3][co + 1] += p3 * v4.y;
        acc[3][co + 2] += p3 * v4.z; acc[3][co + 3] += p3 * v4.w;
      }
      __syncthreads();
    }
  }

  // ---- finalize: divide by l, store ctx ----
  float linv[4];
#pragma unroll
  for (int i = 0; i < 4; ++i) linv[i] = 1.0f / lrow[(ty << 2) + i];
#pragma unroll
  for (int i = 0; i < 4; ++i) {
#pragma unroll
    for (int dc = 0; dc < 4; ++dc) {
      float4 o;
      o.x = acc[i][(dc << 2) + 0] * linv[i];
      o.y = acc[i][(dc << 2) + 1] * linv[i];
      o.z = acc[i][(dc << 2) + 2] * linv[i];
      o.w = acc[i][(dc << 2) + 3] * linv[i];
      *(float4*)(ctx + base + (size_t)(q0 + (ty << 2) + i) * D_ + (dc << 6) + (tx << 2)) = o;
    }
  }
}

// ---------------------------------------------------------------------------
// w[row] = dot(logits[row,:], cv)   — one wave per row, 4 rows per block
// ---------------------------------------------------------------------------
__global__ __launch_bounds__(256) void wdot_kernel(
    const float* __restrict__ logits, const float* __restrict__ cv,
    float* __restrict__ w) {
  const int t    = threadIdx.x;
  const int wave = t >> 6, lane = t & 63;
  const size_t row = (size_t)blockIdx.x * 4 + wave;
  const float4 l4 = *(const float4*)(logits + row * 256 + (lane << 2));
  const float4 c4 = *(const float4*)(cv + (lane << 2));
  float p = l4.x * c4.x + l4.y * c4.y + l4.z * c4.z + l4.w * c4.w;
#pragma unroll
  for (int off = 32; off > 0; off >>= 1) p += __shfl_down(p, off, 64);
  if (lane == 0) w[row] = p;
}

// ---------------------------------------------------------------------------
// softmax over the sequence dim per batch (in place on w) — one block per b
// ---------------------------------------------------------------------------
__global__ __launch_bounds__(256) void seq_softmax_kernel(float* __restrict__ w) {
  __shared__ float red[4];
  const int b = blockIdx.x, t = threadIdx.x;
  const int wave = t >> 6, lane = t & 63;
  float* wb = w + (size_t)b * S_;
  float vals[16];
  float mx = -INFINITY;
#pragma unroll
  for (int i = 0; i < 16; ++i) {
    vals[i] = wb[t + (i << 8)];
    mx = fmaxf(mx, vals[i]);
  }
#pragma unroll
  for (int off = 32; off > 0; off >>= 1) mx = fmaxf(mx, __shfl_xor(mx, off, 64));
  if (lane == 0) red[wave] = mx;
  __syncthreads();
  const float M = fmaxf(fmaxf(red[0], red[1]), fmaxf(red[2], red[3]));
  float sum = 0.f;
#pragma unroll
  for (int i = 0; i < 16; ++i) {
    vals[i] = __expf(vals[i] - M);
    sum += vals[i];
  }
#pragma unroll
  for (int off = 32; off > 0; off >>= 1) sum += __shfl_xor(sum, off, 64);
  __syncthreads();
  if (lane == 0) red[wave] = sum;
  __syncthreads();
  const float inv = 1.0f / (red[0] + red[1] + red[2] + red[3]);
#pragma unroll
  for (int i = 0; i < 16; ++i) wb[t + (i << 8)] = vals[i] * inv;
}

// ---------------------------------------------------------------------------
// out[b,s,:] *= nw[b,s]   (in place on d_out, float4 per thread)
// ---------------------------------------------------------------------------
__global__ __launch_bounds__(256) void scale_kernel(
    float* __restrict__ out, const float* __restrict__ nw) {
  const size_t g = (size_t)blockIdx.x * 256 + threadIdx.x;  // float4 index
  float4* o4 = (float4*)out;
  float4 vv = o4[g];
  const float sc = nw[g >> 6];
  vv.x *= sc; vv.y *= sc; vv.z *= sc; vv.w *= sc;
  o4[g] = vv;
}

// ---------------------------------------------------------------------------
extern "C" void kernel_launch(void* const* d_in, const int* in_sizes, int n_in,
                              void* d_out, int out_size, void* d_ws, size_t ws_size,
                              hipStream_t stream) {
  const float* x  = (const float*)d_in[0];
  const float* Wq = (const float*)d_in[1];
  const float* bq = (const float*)d_in[2];
  const float* Wk = (const float*)d_in[3];
  const float* bk = (const float*)d_in[4];
  const float* Wv = (const float*)d_in[5];
  const float* bv = (const float*)d_in[6];
  const float* Wo = (const float*)d_in[7];
  const float* bo = (const float*)d_in[8];
  const float* cv = (const float*)d_in[9];
  float* out = (float*)d_out;

  const size_t N = (size_t)B_ * S_ * D_;  // 8,388,608
  float* q   = (float*)d_ws;
  float* k   = q + N;
  float* v   = k + N;
  float* ctx = v + N;
  float* w   = ctx + N;  // B*S floats

  const dim3 gg(512, 4);  // (M/64, 256/64)
  gemm_bias_kernel<<<gg, 256, 0, stream>>>(x, Wq, bq, q);
  gemm_bias_kernel<<<gg, 256, 0, stream>>>(x, Wk, bk, k);
  gemm_bias_kernel<<<gg, 256, 0, stream>>>(x, Wv, bv, v);
  flash_attn_kernel<<<dim3(64, 8), 256, 0, stream>>>(q, k, v, ctx);
  gemm_bias_kernel<<<gg, 256, 0, stream>>>(ctx, Wo, bo, out);
  wdot_kernel<<<8192, 256, 0, stream>>>(out, cv, w);
  seq_softmax_kernel<<<8, 256, 0, stream>>>(w);
  scale_kernel<<<8192, 256, 0, stream>>>(out, w);
}

// Round 2
// 3273.439 us; speedup vs baseline: 1.0368x; 1.0368x over previous
//
#include <hip/hip_runtime.h>
#include <math.h>
#include <cstddef>
#include <cstdint>

#define B_ 8
#define S_ 4096
#define D_ 256

// ---------------------------------------------------------------------------
// GEMM: C[M,256] = A[M,256] @ W[256,256] + bias   (fp32)
// Tile 64(M) x 256(N) per block, K chunked by 32. 256 threads as
// (tx=32 n-groups of 8) x (ty=8 m-groups of 8); 8x8 micro-tile per thread.
// A staged transposed [k][m] (reads broadcast per ty); W staged natural
// [k][n] (reads 2x b128 per thread). 64 FMA per 4 b128 -> LDS/VALU ~1.5.
// ---------------------------------------------------------------------------
__global__ __launch_bounds__(256, 2) void gemm_bias_kernel(
    const float* __restrict__ A, const float* __restrict__ W,
    const float* __restrict__ bias, float* __restrict__ C) {
  __shared__ __align__(16) float sA[32 * 68];   // A^T chunk [k][m], pad 68
  __shared__ __align__(16) float sW[32 * 260];  // W chunk [k][n], pad 260
  const int t  = threadIdx.x;
  const int tx = t & 31;   // n-group: cols 8*tx .. 8*tx+7
  const int ty = t >> 5;   // m-group: rows 8*ty .. 8*ty+7
  const size_t m0 = (size_t)blockIdx.x * 64;

  float acc[8][8] = {};

  for (int kc = 0; kc < 8; ++kc) {
    const int k0 = kc << 5;
    __syncthreads();
    // stage A^T: 64 rows x 32 k, 2 float4 per thread, transposed scalar writes
#pragma unroll
    for (int l = 0; l < 2; ++l) {
      const int idx = t + (l << 8);
      const int r = idx >> 3, cf = (idx & 7) << 2;
      const float4 a4 = *(const float4*)(A + (m0 + r) * 256 + k0 + cf);
      sA[(cf + 0) * 68 + r] = a4.x;
      sA[(cf + 1) * 68 + r] = a4.y;
      sA[(cf + 2) * 68 + r] = a4.z;
      sA[(cf + 3) * 68 + r] = a4.w;
    }
    // stage W natural: 32 k-rows x 256 n, 8 float4 per thread
#pragma unroll
    for (int l = 0; l < 8; ++l) {
      const int idx = t + (l << 8);
      const int kr = idx >> 6, nc = (idx & 63) << 2;
      *(float4*)&sW[kr * 260 + nc] =
          *(const float4*)(W + (size_t)(k0 + kr) * 256 + nc);
    }
    __syncthreads();
#pragma unroll
    for (int kk = 0; kk < 32; ++kk) {
      const float4 a0 = *(const float4*)&sA[kk * 68 + (ty << 3)];
      const float4 a1 = *(const float4*)&sA[kk * 68 + (ty << 3) + 4];
      const float4 b0 = *(const float4*)&sW[kk * 260 + (tx << 3)];
      const float4 b1 = *(const float4*)&sW[kk * 260 + (tx << 3) + 4];
      const float av[8] = {a0.x, a0.y, a0.z, a0.w, a1.x, a1.y, a1.z, a1.w};
      const float bv[8] = {b0.x, b0.y, b0.z, b0.w, b1.x, b1.y, b1.z, b1.w};
#pragma unroll
      for (int i = 0; i < 8; ++i)
#pragma unroll
        for (int c = 0; c < 8; ++c) acc[i][c] += av[i] * bv[c];
    }
  }

  const float4 bb0 = *(const float4*)(bias + (tx << 3));
  const float4 bb1 = *(const float4*)(bias + (tx << 3) + 4);
#pragma unroll
  for (int i = 0; i < 8; ++i) {
    float4 o0, o1;
    o0.x = acc[i][0] + bb0.x; o0.y = acc[i][1] + bb0.y;
    o0.z = acc[i][2] + bb0.z; o0.w = acc[i][3] + bb0.w;
    o1.x = acc[i][4] + bb1.x; o1.y = acc[i][5] + bb1.y;
    o1.z = acc[i][6] + bb1.z; o1.w = acc[i][7] + bb1.w;
    float* cp = C + (m0 + (ty << 3) + i) * 256 + (tx << 3);
    *(float4*)cp = o0;
    *(float4*)(cp + 4) = o1;
  }
}

// ---------------------------------------------------------------------------
// Flash attention, fp32.  Grid (S/64, B), 256 threads.
// BQ=64 q-rows per block; K/V streamed in 256-col tiles (16 outer iters).
// Thread grid: tx=32 (8 j-cols each in scores; 8 d-cols each in PV),
// ty=8 (8 q-rows each). 8x8 micro-tile in both phases -> LDS/VALU ~1.5.
// Softmax fully in registers: each q-row lives on 32 lanes sharing ty
// (xor-shuffle reduce over lane bits 0..4). P goes to LDS only in 32-j
// chunks (float4 writes, b128 broadcast reads).
// LDS = (32*68 + 32*260)*4 = 42 KB, phase-aliased (Qt|pT, Kt|V).
// ---------------------------------------------------------------------------
__global__ __launch_bounds__(256, 2) void flash_attn_kernel(
    const float* __restrict__ q, const float* __restrict__ k,
    const float* __restrict__ v, float* __restrict__ ctx) {
  __shared__ __align__(16) float sA[32 * 68];   // Q^T chunk | pT^T chunk
  __shared__ __align__(16) float sB[32 * 260];  // K^T chunk | V chunk
  const int t  = threadIdx.x;
  const int tx = t & 31;
  const int ty = t >> 5;
  const int q0 = blockIdx.x * 64;
  const size_t base = (size_t)blockIdx.y * S_ * D_;

  float acc[8][8] = {};   // ctx accumulator: rows 8ty+i, d-cols 8tx+c
  float m_i[8], l_i[8];
#pragma unroll
  for (int i = 0; i < 8; ++i) { m_i[i] = -INFINITY; l_i[i] = 0.f; }

  for (int jt = 0; jt < 16; ++jt) {
    const int j0 = jt << 8;
    float s[8][8] = {};  // scores: rows 8ty+i, j-cols 8tx+c

    // ---- scores: S = (Q/16) @ K^T, D chunked by 32 ----
    for (int dc = 0; dc < 8; ++dc) {
      const int d0 = dc << 5;
      __syncthreads();
      // stage Q^T (pre-scaled by 1/sqrt(D)): 2 float4/thread
#pragma unroll
      for (int l = 0; l < 2; ++l) {
        const int idx = t + (l << 8);
        const int r = idx >> 3, cf = (idx & 7) << 2;
        const float4 qv =
            *(const float4*)(q + base + (size_t)(q0 + r) * D_ + d0 + cf);
        sA[(cf + 0) * 68 + r] = qv.x * 0.0625f;
        sA[(cf + 1) * 68 + r] = qv.y * 0.0625f;
        sA[(cf + 2) * 68 + r] = qv.z * 0.0625f;
        sA[(cf + 3) * 68 + r] = qv.w * 0.0625f;
      }
      // stage K^T: 256 j-rows x 32 d, 8 float4/thread
#pragma unroll
      for (int l = 0; l < 8; ++l) {
        const int idx = t + (l << 8);
        const int j = idx >> 3, cf = (idx & 7) << 2;
        const float4 kv =
            *(const float4*)(k + base + (size_t)(j0 + j) * D_ + d0 + cf);
        sB[(cf + 0) * 260 + j] = kv.x;
        sB[(cf + 1) * 260 + j] = kv.y;
        sB[(cf + 2) * 260 + j] = kv.z;
        sB[(cf + 3) * 260 + j] = kv.w;
      }
      __syncthreads();
#pragma unroll
      for (int dk = 0; dk < 32; ++dk) {
        const float4 a0 = *(const float4*)&sA[dk * 68 + (ty << 3)];
        const float4 a1 = *(const float4*)&sA[dk * 68 + (ty << 3) + 4];
        const float4 b0 = *(const float4*)&sB[dk * 260 + (tx << 3)];
        const float4 b1 = *(const float4*)&sB[dk * 260 + (tx << 3) + 4];
        const float av[8] = {a0.x, a0.y, a0.z, a0.w, a1.x, a1.y, a1.z, a1.w};
        const float bv[8] = {b0.x, b0.y, b0.z, b0.w, b1.x, b1.y, b1.z, b1.w};
#pragma unroll
        for (int i = 0; i < 8; ++i)
#pragma unroll
          for (int c = 0; c < 8; ++c) s[i][c] += av[i] * bv[c];
      }
    }

    // ---- online softmax, fully in registers (32-lane row groups) ----
#pragma unroll
    for (int i = 0; i < 8; ++i) {
      float mx = s[i][0];
#pragma unroll
      for (int c = 1; c < 8; ++c) mx = fmaxf(mx, s[i][c]);
#pragma unroll
      for (int off = 1; off <= 16; off <<= 1)
        mx = fmaxf(mx, __shfl_xor(mx, off, 64));
      const float mnew = fmaxf(m_i[i], mx);
      const float alpha = __expf(m_i[i] - mnew);
      m_i[i] = mnew;
      float sum = 0.f;
#pragma unroll
      for (int c = 0; c < 8; ++c) {
        s[i][c] = __expf(s[i][c] - mnew);
        sum += s[i][c];
      }
#pragma unroll
      for (int off = 1; off <= 16; off <<= 1)
        sum += __shfl_xor(sum, off, 64);
      l_i[i] = l_i[i] * alpha + sum;
#pragma unroll
      for (int c = 0; c < 8; ++c) acc[i][c] *= alpha;
    }

    // ---- PV: ctx += P @ V, j in 8 chunks of 32 ----
    for (int sj = 0; sj < 8; ++sj) {
      __syncthreads();
      // write P^T chunk: threads with tx in [4sj, 4sj+4), float4 stores
      if ((tx >> 2) == sj) {
        const int txl = tx & 3;
#pragma unroll
        for (int c = 0; c < 8; ++c) {
          const int jl = (txl << 3) + c;
          float4 p0, p1;
          p0.x = s[0][c]; p0.y = s[1][c]; p0.z = s[2][c]; p0.w = s[3][c];
          p1.x = s[4][c]; p1.y = s[5][c]; p1.z = s[6][c]; p1.w = s[7][c];
          *(float4*)&sA[jl * 68 + (ty << 3)]     = p0;
          *(float4*)&sA[jl * 68 + (ty << 3) + 4] = p1;
        }
      }
      // stage V chunk [32 j][256 d], natural layout, 8 float4/thread
#pragma unroll
      for (int l = 0; l < 8; ++l) {
        const int idx = t + (l << 8);
        const int jr = idx >> 6, nc = (idx & 63) << 2;
        *(float4*)&sB[jr * 260 + nc] = *(const float4*)(
            v + base + (size_t)(j0 + (sj << 5) + jr) * D_ + nc);
      }
      __syncthreads();
#pragma unroll
      for (int jj = 0; jj < 32; ++jj) {
        const float4 p0 = *(const float4*)&sA[jj * 68 + (ty << 3)];
        const float4 p1 = *(const float4*)&sA[jj * 68 + (ty << 3) + 4];
        const float4 v0 = *(const float4*)&sB[jj * 260 + (tx << 3)];
        const float4 v1 = *(const float4*)&sB[jj * 260 + (tx << 3) + 4];
        const float pv[8] = {p0.x, p0.y, p0.z, p0.w, p1.x, p1.y, p1.z, p1.w};
        const float vv[8] = {v0.x, v0.y, v0.z, v0.w, v1.x, v1.y, v1.z, v1.w};
#pragma unroll
        for (int i = 0; i < 8; ++i)
#pragma unroll
          for (int c = 0; c < 8; ++c) acc[i][c] += pv[i] * vv[c];
      }
    }
  }

  // ---- finalize: divide by l, store ----
#pragma unroll
  for (int i = 0; i < 8; ++i) {
    const float linv = 1.0f / l_i[i];
    float4 o0, o1;
    o0.x = acc[i][0] * linv; o0.y = acc[i][1] * linv;
    o0.z = acc[i][2] * linv; o0.w = acc[i][3] * linv;
    o1.x = acc[i][4] * linv; o1.y = acc[i][5] * linv;
    o1.z = acc[i][6] * linv; o1.w = acc[i][7] * linv;
    float* cp = ctx + base + (size_t)(q0 + (ty << 3) + i) * D_ + (tx << 3);
    *(float4*)cp = o0;
    *(float4*)(cp + 4) = o1;
  }
}

// ---------------------------------------------------------------------------
// w[row] = dot(logits[row,:], cv)   — one wave per row, 4 rows per block
// ---------------------------------------------------------------------------
__global__ __launch_bounds__(256) void wdot_kernel(
    const float* __restrict__ logits, const float* __restrict__ cv,
    float* __restrict__ w) {
  const int t    = threadIdx.x;
  const int wave = t >> 6, lane = t & 63;
  const size_t row = (size_t)blockIdx.x * 4 + wave;
  const float4 l4 = *(const float4*)(logits + row * 256 + (lane << 2));
  const float4 c4 = *(const float4*)(cv + (lane << 2));
  float p = l4.x * c4.x + l4.y * c4.y + l4.z * c4.z + l4.w * c4.w;
#pragma unroll
  for (int off = 32; off > 0; off >>= 1) p += __shfl_down(p, off, 64);
  if (lane == 0) w[row] = p;
}

// ---------------------------------------------------------------------------
// softmax over the sequence dim per batch (in place on w) — one block per b
// ---------------------------------------------------------------------------
__global__ __launch_bounds__(256) void seq_softmax_kernel(float* __restrict__ w) {
  __shared__ float red[4];
  const int b = blockIdx.x, t = threadIdx.x;
  const int wave = t >> 6, lane = t & 63;
  float* wb = w + (size_t)b * S_;
  float vals[16];
  float mx = -INFINITY;
#pragma unroll
  for (int i = 0; i < 16; ++i) {
    vals[i] = wb[t + (i << 8)];
    mx = fmaxf(mx, vals[i]);
  }
#pragma unroll
  for (int off = 32; off > 0; off >>= 1) mx = fmaxf(mx, __shfl_xor(mx, off, 64));
  if (lane == 0) red[wave] = mx;
  __syncthreads();
  const float M = fmaxf(fmaxf(red[0], red[1]), fmaxf(red[2], red[3]));
  float sum = 0.f;
#pragma unroll
  for (int i = 0; i < 16; ++i) {
    vals[i] = __expf(vals[i] - M);
    sum += vals[i];
  }
#pragma unroll
  for (int off = 32; off > 0; off >>= 1) sum += __shfl_xor(sum, off, 64);
  __syncthreads();
  if (lane == 0) red[wave] = sum;
  __syncthreads();
  const float inv = 1.0f / (red[0] + red[1] + red[2] + red[3]);
#pragma unroll
  for (int i = 0; i < 16; ++i) wb[t + (i << 8)] = vals[i] * inv;
}

// ---------------------------------------------------------------------------
// out[b,s,:] *= nw[b,s]   (in place on d_out, float4 per thread)
// ---------------------------------------------------------------------------
__global__ __launch_bounds__(256) void scale_kernel(
    float* __restrict__ out, const float* __restrict__ nw) {
  const size_t g = (size_t)blockIdx.x * 256 + threadIdx.x;  // float4 index
  float4* o4 = (float4*)out;
  float4 vv = o4[g];
  const float sc = nw[g >> 6];
  vv.x *= sc; vv.y *= sc; vv.z *= sc; vv.w *= sc;
  o4[g] = vv;
}

// ---------------------------------------------------------------------------
extern "C" void kernel_launch(void* const* d_in, const int* in_sizes, int n_in,
                              void* d_out, int out_size, void* d_ws, size_t ws_size,
                              hipStream_t stream) {
  const float* x  = (const float*)d_in[0];
  const float* Wq = (const float*)d_in[1];
  const float* bq = (const float*)d_in[2];
  const float* Wk = (const float*)d_in[3];
  const float* bk = (const float*)d_in[4];
  const float* Wv = (const float*)d_in[5];
  const float* bv = (const float*)d_in[6];
  const float* Wo = (const float*)d_in[7];
  const float* bo = (const float*)d_in[8];
  const float* cv = (const float*)d_in[9];
  float* out = (float*)d_out;

  const size_t N = (size_t)B_ * S_ * D_;  // 8,388,608
  float* q   = (float*)d_ws;
  float* k   = q + N;
  float* v   = k + N;
  float* ctx = v + N;
  float* w   = ctx + N;  // B*S floats

  gemm_bias_kernel<<<512, 256, 0, stream>>>(x, Wq, bq, q);
  gemm_bias_kernel<<<512, 256, 0, stream>>>(x, Wk, bk, k);
  gemm_bias_kernel<<<512, 256, 0, stream>>>(x, Wv, bv, v);
  flash_attn_kernel<<<dim3(64, 8), 256, 0, stream>>>(q, k, v, ctx);
  gemm_bias_kernel<<<512, 256, 0, stream>>>(ctx, Wo, bo, out);
  wdot_kernel<<<8192, 256, 0, stream>>>(out, cv, w);
  seq_softmax_kernel<<<8, 256, 0, stream>>>(w);
  scale_kernel<<<8192, 256, 0, stream>>>(out, w);
}